// Round 17
// baseline (410.525 us; speedup 1.0000x reference)
//
#include <hip/hip_runtime.h>
#include <math.h>

#define CCH 64
#define HH 480
#define WW 360
#define KK 32
#define HR 64
#define WR 2048
#define NPIX (HH*WW)            // 172800
#define RFNPIX (HR*WR)          // 131072
#define ZOFF 16777216u          // byte offset of zero line in rfT16
#define NEGOFF 16777344u        // byte offset of -3.4e38 sentinel line

typedef __attribute__((ext_vector_type(8))) short short8;
typedef __attribute__((ext_vector_type(4))) float f32x4;
typedef __attribute__((ext_vector_type(4))) int  int4_;

__device__ __forceinline__ ushort f2bf(float f) {        // RTN f32->bf16
    uint u = __float_as_uint(f);
    return (ushort)((u + 0x7fffu + ((u >> 16) & 1u)) >> 16);
}

// ---------------------------------------------------------------------------
// Weight prep: pack conv weights into MFMA A-fragment order, bf16.
// ---------------------------------------------------------------------------
__global__ __launch_bounds__(256) void k_wprep(const float* __restrict__ fw,
                                               const float* __restrict__ aw,
                                               ushort* __restrict__ wA1,
                                               ushort* __restrict__ wA2) {
    int t = blockIdx.x * 256 + threadIdx.x;
    if (t < 73728) {                                   // conv1: 4 chunks (128 ci)
        int j = t & 7, ln = (t >> 3) & 63, Mf = (t >> 9) & 3, rem = t >> 11;
        int tap = rem % 9, c = rem / 9;
        int o = Mf * 16 + (ln & 15);
        int ci = c * 32 + ((ln >> 4) & 3) * 8 + j;
        wA1[t] = f2bf(fw[(o * 128 + ci) * 9 + tap]);
    } else if (t < 73728 + 36864) {                    // conv2: 2 chunks (64 ci)
        int i = t - 73728;
        int j = i & 7, ln = (i >> 3) & 63, Mf = (i >> 9) & 3, rem = i >> 11;
        int tap = rem % 9, c = rem / 9;
        int o = Mf * 16 + (ln & 15);
        int ci = c * 32 + ((ln >> 4) & 3) * 8 + j;
        wA2[i] = f2bf(aw[(o * 64 + ci) * 9 + tap]);
    }
}

// ---------------------------------------------------------------------------
// Transpose f32 [64][npix] -> bf16 channel-last [npix][rowShorts] (cols 0..63)
// ---------------------------------------------------------------------------
__global__ __launch_bounds__(256) void k_tr(const float* __restrict__ src,
                                            ushort* __restrict__ dst,
                                            int npix, int rowShorts) {
    __shared__ float lds[64][65];
    int t = threadIdx.x;
    int pix0 = blockIdx.x * 64;
    int lx = t & 63, ty = t >> 6;
    #pragma unroll
    for (int cc = 0; cc < 64; cc += 4) {
        int c = cc + ty;
        lds[c][lx] = src[(size_t)c * npix + pix0 + lx];
    }
    __syncthreads();
    int cp = t & 31, po = t >> 5;        // cp = channel pair, po = pixel offset
    #pragma unroll
    for (int pl = po; pl < 64; pl += 8) {
        uint u = (uint)f2bf(lds[2 * cp][pl]) | ((uint)f2bf(lds[2 * cp + 1][pl]) << 16);
        *(uint*)(dst + (size_t)(pix0 + pl) * rowShorts + cp * 2) = u;
    }
}

// zero line at ZOFF, -3.4e38 (bf16 pair pattern) line at NEGOFF
__global__ void k_zero(uint* __restrict__ rft32) {
    int t = threadIdx.x;
    if (t < 32)       rft32[(ZOFF >> 2) + t] = 0;
    else if (t < 64)  rft32[(NEGOFF >> 2) + (t - 32)] = 0xFF7FFF7Fu;
}

// ---------------------------------------------------------------------------
// Flow sampling v9 (round-12 proven: 112.5us/dispatch, FETCH 0.39GB): two
// sequential dispatches (sel=0: table rows [0,32); sel=1: [32,64)) -- launch
// boundary = free global phase barrier halving the live footprint to 8.4MB.
// Max merged through xin bf16. 2-ballot partition; trip = max(cntA,cntB);
// surplus iters read NEGOFF sentinel (w00=1, -3.4e38, neutral, L1-resident).
// ---------------------------------------------------------------------------
__global__ __launch_bounds__(256) void k_sample(const float* __restrict__ flow,
                                                const char* __restrict__ rftb,
                                                ushort* __restrict__ xin,
                                                int sel, int mergePrev) {
    __shared__ __align__(16) uint pbuf[4][2][33][8];   // [wave][half][entry][(off,w)x4]
    int tid = threadIdx.x;
    int ln = tid & 63;
    int wid = tid >> 6;
    int half = ln >> 5;
    int gwave = blockIdx.x * 4 + wid;

    // ---- prep (per-lane: one (pixel,k)) ----
    int k = ln & 31;
    int pix = gwave * 2 + half;
    const float* fp = flow + (size_t)pix * 64 + 2 * k;
    float gy = __builtin_nontemporal_load(fp);
    float gx = __builtin_nontemporal_load(fp + 1);
    float ix = fmaf(gx, 1024.f, 1023.5f);
    float iy = fmaf(gy, 32.f, 31.5f);
    float xf = floorf(ix), yf = floorf(iy);
    float wx = ix - xf, wy = iy - yf;
    int x0 = (int)xf, y0 = (int)yf;
    bool xv0 = (unsigned)x0 < (unsigned)WR;
    bool xv1 = (unsigned)(x0 + 1) < (unsigned)WR;
    bool yv0 = (unsigned)y0 < (unsigned)HR;
    bool yv1 = (unsigned)(y0 + 1) < (unsigned)HR;
    int xc0 = x0 < 0 ? 0 : x0;
    int xc1 = x0 + 1 > WR - 1 ? WR - 1 : x0 + 1;
    int yc0 = y0 < 0 ? 0 : y0;
    int yc1 = y0 + 1 > HR - 1 ? HR - 1 : y0 + 1;
    uint o00 = (xv0 && yv0) ? (uint)(((yc0 << 11) + xc0) << 7) : ZOFF;
    uint o01 = (xv1 && yv0) ? (uint)(((yc0 << 11) + xc1) << 7) : ZOFF;
    uint o10 = (xv0 && yv1) ? (uint)(((yc1 << 11) + xc0) << 7) : ZOFF;
    uint o11 = (xv1 && yv1) ? (uint)(((yc1 << 11) + xc1) << 7) : ZOFF;
    float w00 = (1.f - wy) * (1.f - wx);
    float w01 = (1.f - wy) * wx;
    float w10 = wy * (1.f - wx);
    float w11 = wy * wx;

    // ---- 2-way partition by slice (in-range compacted to front) ----
    bool isIn = ((yc0 >> 5) == sel);
    unsigned long long hm = half ? 0xFFFFFFFF00000000ull : 0x00000000FFFFFFFFull;
    unsigned long long lower = (1ull << ln) - 1ull;
    unsigned long long balIn = __ballot(isIn);
    int cntIn = __popcll(balIn & hm);
    int rankIn = __popcll(balIn & hm & lower);
    int rankOut = __popcll(~balIn & hm & lower);
    int pos = isIn ? rankIn : (cntIn + rankOut);
    *(int4_*)&pbuf[wid][half][pos][0] =
        (int4_){(int)o00, __float_as_int(w00), (int)o01, __float_as_int(w01)};
    *(int4_*)&pbuf[wid][half][pos][4] =
        (int4_){(int)o10, __float_as_int(w10), (int)o11, __float_as_int(w11)};
    if ((ln & 31) == 0) {                                // dummy entry at pos 32
        *(int4_*)&pbuf[wid][half][32][0] =
            (int4_){(int)NEGOFF, __float_as_int(1.0f), (int)ZOFF, 0};
        *(int4_*)&pbuf[wid][half][32][4] = (int4_){(int)ZOFF, 0, (int)ZOFF, 0};
    }
    __syncthreads();

    uint laneByte = (uint)((ln & 31) * 4);
    const uint* pb = &pbuf[wid][half][0][0];
    float mLo = -3.0e38f, mHi = -3.0e38f;
    int cA = __builtin_amdgcn_readlane(cntIn, 0);
    int cB = __builtin_amdgcn_readlane(cntIn, 32);
    int trip = cA > cB ? cA : cB;

    for (int i = 0; i < trip; i++) {
        int idx = (i < cntIn) ? i : 32;
        const uint* e = pb + idx * 8;
        uint2 e0 = *(const uint2*)(e + 0);               // ds_read_b64, bcast/half
        uint2 e1 = *(const uint2*)(e + 2);
        uint2 e2 = *(const uint2*)(e + 4);
        uint2 e3 = *(const uint2*)(e + 6);
        uint d0 = *(const uint*)(rftb + (e0.x + laneByte));
        uint d1 = *(const uint*)(rftb + (e1.x + laneByte));
        uint d2 = *(const uint*)(rftb + (e2.x + laneByte));
        uint d3 = *(const uint*)(rftb + (e3.x + laneByte));
        float W0 = __uint_as_float(e0.y);
        float W1 = __uint_as_float(e1.y);
        float W2 = __uint_as_float(e2.y);
        float W3 = __uint_as_float(e3.y);

        float vlo = W0 * __uint_as_float(d0 << 16);
        vlo = fmaf(W1, __uint_as_float(d1 << 16), vlo);
        vlo = fmaf(W2, __uint_as_float(d2 << 16), vlo);
        vlo = fmaf(W3, __uint_as_float(d3 << 16), vlo);
        float vhi = W0 * __uint_as_float(d0 & 0xffff0000u);
        vhi = fmaf(W1, __uint_as_float(d1 & 0xffff0000u), vhi);
        vhi = fmaf(W2, __uint_as_float(d2 & 0xffff0000u), vhi);
        vhi = fmaf(W3, __uint_as_float(d3 & 0xffff0000u), vhi);
        mLo = fmaxf(mLo, vlo);
        mHi = fmaxf(mHi, vhi);
    }

    uint* xp = (uint*)((char*)xin + (size_t)pix * 256 + 128 + (ln & 31) * 4);
    if (mergePrev) {                                     // merge dispatch A's max
        uint cur = __builtin_nontemporal_load(xp);
        mLo = fmaxf(mLo, __uint_as_float(cur << 16));
        mHi = fmaxf(mHi, __uint_as_float(cur & 0xffff0000u));
    }
    uint outw;
    asm("v_cvt_pk_bf16_f32 %0, %1, %2" : "=v"(outw) : "v"(mLo), "v"(mHi));
    __builtin_nontemporal_store(outw, xp);
}

// ---------------------------------------------------------------------------
// conv1 v2: implicit-GEMM MFMA with B-fragments loaded DIRECTLY from global
// xin (no LDS, no barriers, no staging). The MFMA B layout maps exactly onto
// channel-last xin: lane ln reads 8 channels (kq*8) of one pixel = one 16B
// load at xin + gpix*128 + c*32 + kq*8. dw/nf-overlap is L1-served; invalid
// rows skipped as uniform branch (reference zero-pads vertically). Wrapped
// pixel offsets precomputed once. LDS=0 -> higher occupancy, full pipelining.
// ---------------------------------------------------------------------------
__global__ __launch_bounds__(256) void k_mconv1(const ushort* __restrict__ xin,
                                                const ushort* __restrict__ wA,
                                                const float* __restrict__ g,
                                                const float* __restrict__ b,
                                                const float* __restrict__ mn,
                                                const float* __restrict__ vr,
                                                ushort* __restrict__ res_bf) {
    int tid = threadIdx.x;
    int h = blockIdx.x >> 1, w0 = (blockIdx.x & 1) * 180;
    int wid = tid >> 6, ln = tid & 63;
    int kq = (ln >> 4) & 3;
    int nl = ln & 15;

    int poff[3][3];                                      // wrapped pixel*128
    #pragma unroll
    for (int dw = 0; dw < 3; dw++)
        #pragma unroll
        for (int nf = 0; nf < 3; nf++) {
            int gw = w0 + wid * 48 + nf * 16 + nl + dw - 1;
            if (gw < 0) gw += WW;
            if (gw >= WW) gw -= WW;
            poff[dw][nf] = gw * 128;
        }

    f32x4 acc[4][3];
    #pragma unroll
    for (int m = 0; m < 4; m++)
        #pragma unroll
        for (int nf = 0; nf < 3; nf++) acc[m][nf] = (f32x4){0.f, 0.f, 0.f, 0.f};

    for (int c = 0; c < 4; c++) {
        #pragma unroll
        for (int dh = 0; dh < 3; dh++) {
            int gh = h + dh - 1;
            if ((unsigned)gh >= (unsigned)HH) continue;  // uniform skip = zero pad
            const ushort* rowp = xin + (size_t)gh * (WW * 128) + c * 32 + kq * 8;
            #pragma unroll
            for (int dw = 0; dw < 3; dw++) {
                int tap = dh * 3 + dw;
                short8 aF[4];
                #pragma unroll
                for (int m = 0; m < 4; m++)
                    aF[m] = *(const short8*)(wA + (size_t)(((c * 9 + tap) * 4 + m) * 64 + ln) * 8);
                short8 bF[3];
                #pragma unroll
                for (int nf = 0; nf < 3; nf++)
                    bF[nf] = *(const short8*)(rowp + poff[dw][nf]);
                #pragma unroll
                for (int m = 0; m < 4; m++)
                    #pragma unroll
                    for (int nf = 0; nf < 3; nf++)
                        acc[m][nf] = __builtin_amdgcn_mfma_f32_16x16x32_bf16(aF[m], bF[nf], acc[m][nf], 0, 0, 0);
            }
        }
    }
    // epilogue: BN + ReLU -> res_bf[p][o] (bf16, paired stores)
    #pragma unroll
    for (int m = 0; m < 4; m++) {
        int ob = m * 16 + kq * 4;
        float sc0 = g[ob]     * rsqrtf(vr[ob]     + 1e-5f);
        float sc1 = g[ob + 1] * rsqrtf(vr[ob + 1] + 1e-5f);
        float sc2 = g[ob + 2] * rsqrtf(vr[ob + 2] + 1e-5f);
        float sc3 = g[ob + 3] * rsqrtf(vr[ob + 3] + 1e-5f);
        float bi0 = b[ob]     - mn[ob]     * sc0;
        float bi1 = b[ob + 1] - mn[ob + 1] * sc1;
        float bi2 = b[ob + 2] - mn[ob + 2] * sc2;
        float bi3 = b[ob + 3] - mn[ob + 3] * sc3;
        #pragma unroll
        for (int nf = 0; nf < 3; nf++) {
            int n = wid * 48 + nf * 16 + nl;
            if (n < 180) {
                int P = h * WW + w0 + n;
                float v0 = fmaxf(fmaf(acc[m][nf][0], sc0, bi0), 0.f);
                float v1 = fmaxf(fmaf(acc[m][nf][1], sc1, bi1), 0.f);
                float v2 = fmaxf(fmaf(acc[m][nf][2], sc2, bi2), 0.f);
                float v3 = fmaxf(fmaf(acc[m][nf][3], sc3, bi3), 0.f);
                uint lo, hi;
                asm("v_cvt_pk_bf16_f32 %0, %1, %2" : "=v"(lo) : "v"(v0), "v"(v1));
                asm("v_cvt_pk_bf16_f32 %0, %1, %2" : "=v"(hi) : "v"(v2), "v"(v3));
                uint2 pk; pk.x = lo; pk.y = hi;
                *(uint2*)(res_bf + (size_t)P * 64 + ob) = pk;
            }
        }
    }
}

// ---------------------------------------------------------------------------
// conv2 v2: same direct-global B-fragment scheme on res_bf (row stride 64ch),
// BN + channel softmax + final out = polar + res*att.
// ---------------------------------------------------------------------------
__global__ __launch_bounds__(256) void k_mconv2(const ushort* __restrict__ res_bf,
                                                const float* __restrict__ polar,
                                                const ushort* __restrict__ wA,
                                                const float* __restrict__ g,
                                                const float* __restrict__ b,
                                                const float* __restrict__ mn,
                                                const float* __restrict__ vr,
                                                float* __restrict__ out) {
    int tid = threadIdx.x;
    int h = blockIdx.x >> 1, w0 = (blockIdx.x & 1) * 180;
    int wid = tid >> 6, ln = tid & 63;
    int kq = (ln >> 4) & 3;
    int nl = ln & 15;

    int poff[3][3];                                      // wrapped pixel*64
    #pragma unroll
    for (int dw = 0; dw < 3; dw++)
        #pragma unroll
        for (int nf = 0; nf < 3; nf++) {
            int gw = w0 + wid * 48 + nf * 16 + nl + dw - 1;
            if (gw < 0) gw += WW;
            if (gw >= WW) gw -= WW;
            poff[dw][nf] = gw * 64;
        }

    f32x4 acc[4][3];
    #pragma unroll
    for (int m = 0; m < 4; m++)
        #pragma unroll
        for (int nf = 0; nf < 3; nf++) acc[m][nf] = (f32x4){0.f, 0.f, 0.f, 0.f};

    for (int c = 0; c < 2; c++) {
        #pragma unroll
        for (int dh = 0; dh < 3; dh++) {
            int gh = h + dh - 1;
            if ((unsigned)gh >= (unsigned)HH) continue;
            const ushort* rowp = res_bf + (size_t)gh * (WW * 64) + c * 32 + kq * 8;
            #pragma unroll
            for (int dw = 0; dw < 3; dw++) {
                int tap = dh * 3 + dw;
                short8 aF[4];
                #pragma unroll
                for (int m = 0; m < 4; m++)
                    aF[m] = *(const short8*)(wA + (size_t)(((c * 9 + tap) * 4 + m) * 64 + ln) * 8);
                short8 bF[3];
                #pragma unroll
                for (int nf = 0; nf < 3; nf++)
                    bF[nf] = *(const short8*)(rowp + poff[dw][nf]);
                #pragma unroll
                for (int m = 0; m < 4; m++)
                    #pragma unroll
                    for (int nf = 0; nf < 3; nf++)
                        acc[m][nf] = __builtin_amdgcn_mfma_f32_16x16x32_bf16(aF[m], bF[nf], acc[m][nf], 0, 0, 0);
            }
        }
    }
    // epilogue: BN -> softmax over 64 channels -> out = polar + res*att
    #pragma unroll
    for (int m = 0; m < 4; m++) {
        #pragma unroll
        for (int reg = 0; reg < 4; reg++) {
            int o = m * 16 + kq * 4 + reg;
            float sc = g[o] * rsqrtf(vr[o] + 1e-5f);
            float bi = b[o] - mn[o] * sc;
            #pragma unroll
            for (int nf = 0; nf < 3; nf++)
                acc[m][nf][reg] = fmaf(acc[m][nf][reg], sc, bi);
        }
    }
    #pragma unroll
    for (int nf = 0; nf < 3; nf++) {
        float mx = -3.0e38f;
        #pragma unroll
        for (int m = 0; m < 4; m++)
            #pragma unroll
            for (int reg = 0; reg < 4; reg++) mx = fmaxf(mx, acc[m][nf][reg]);
        mx = fmaxf(mx, __shfl_xor(mx, 16));
        mx = fmaxf(mx, __shfl_xor(mx, 32));
        float s = 0.f;
        #pragma unroll
        for (int m = 0; m < 4; m++)
            #pragma unroll
            for (int reg = 0; reg < 4; reg++) {
                float e = __expf(acc[m][nf][reg] - mx);
                acc[m][nf][reg] = e;
                s += e;
            }
        s += __shfl_xor(s, 16);
        s += __shfl_xor(s, 32);
        float rinv = 1.f / s;
        int n = wid * 48 + nf * 16 + nl;
        if (n < 180) {
            int P = h * WW + w0 + n;
            #pragma unroll
            for (int m = 0; m < 4; m++)
                #pragma unroll
                for (int reg = 0; reg < 4; reg++) {
                    int o = m * 16 + kq * 4 + reg;
                    float att = acc[m][nf][reg] * rinv;
                    float rv = __uint_as_float((uint)res_bf[(size_t)P * 64 + o] << 16);
                    out[(size_t)o * NPIX + P] =
                        fmaf(rv, att, polar[(size_t)o * NPIX + P]);
                }
        }
    }
}

// ---------------------------------------------------------------------------
extern "C" void kernel_launch(void* const* d_in, const int* in_sizes, int n_in,
                              void* d_out, int out_size, void* d_ws, size_t ws_size,
                              hipStream_t stream) {
    const float* flow  = (const float*)d_in[0];
    const float* polar = (const float*)d_in[1];
    const float* rf    = (const float*)d_in[2];
    const float* fw    = (const float*)d_in[3];
    const float* fg    = (const float*)d_in[4];
    const float* fb    = (const float*)d_in[5];
    const float* fm    = (const float*)d_in[6];
    const float* fv    = (const float*)d_in[7];
    const float* aw    = (const float*)d_in[8];
    const float* ag    = (const float*)d_in[9];
    const float* ab    = (const float*)d_in[10];
    const float* am    = (const float*)d_in[11];
    const float* av    = (const float*)d_in[12];
    float* out = (float*)d_out;

    char* wsb = (char*)d_ws;
    ushort* xin    = (ushort*)wsb;                        // [NPIX][128] bf16 = 44,236,800 B
    ushort* rft    = (ushort*)(wsb + 44236800);           // [RFNPIX][64] bf16 + sentinel lines
    ushort* res_bf = (ushort*)(wsb + 61014272);           // [NPIX][64] bf16 = 22,118,400 B
    ushort* wA1    = (ushort*)(wsb + 83132672);           // 147,456 B
    ushort* wA2    = wA1 + 73728;                         // 73,728 B

    k_wprep<<<432, 256, 0, stream>>>(fw, aw, wA1, wA2);
    k_tr<<<NPIX / 64, 256, 0, stream>>>(polar, xin, NPIX, 128);
    k_tr<<<RFNPIX / 64, 256, 0, stream>>>(rf, rft, RFNPIX, 64);
    k_zero<<<1, 64, 0, stream>>>((uint*)rft);
    k_sample<<<NPIX / 8, 256, 0, stream>>>(flow, (const char*)rft, xin, 0, 0);
    k_sample<<<NPIX / 8, 256, 0, stream>>>(flow, (const char*)rft, xin, 1, 1);
    k_mconv1<<<960, 256, 0, stream>>>(xin, wA1, fg, fb, fm, fv, res_bf);
    k_mconv2<<<960, 256, 0, stream>>>(res_bf, polar, wA2, ag, ab, am, av, out);
}

// Round 18
// 363.820 us; speedup vs baseline: 1.1284x; 1.1284x over previous
//
#include <hip/hip_runtime.h>
#include <math.h>

#define CCH 64
#define HH 480
#define WW 360
#define KK 32
#define HR 64
#define WR 2048
#define NPIX (HH*WW)            // 172800
#define RFNPIX (HR*WR)          // 131072
#define ZOFF 16777216u          // byte offset of zero line in rfT16
#define NEGOFF 16777344u        // byte offset of -3.4e38 sentinel line

typedef __attribute__((ext_vector_type(8))) short short8;
typedef __attribute__((ext_vector_type(4))) float f32x4;
typedef __attribute__((ext_vector_type(4))) int  int4_;

__device__ __forceinline__ ushort f2bf(float f) {        // RTN f32->bf16
    uint u = __float_as_uint(f);
    return (ushort)((u + 0x7fffu + ((u >> 16) & 1u)) >> 16);
}

// ---------------------------------------------------------------------------
// Weight prep: pack conv weights into MFMA A-fragment order, bf16.
// ---------------------------------------------------------------------------
__global__ __launch_bounds__(256) void k_wprep(const float* __restrict__ fw,
                                               const float* __restrict__ aw,
                                               ushort* __restrict__ wA1,
                                               ushort* __restrict__ wA2) {
    int t = blockIdx.x * 256 + threadIdx.x;
    if (t < 73728) {                                   // conv1: 4 chunks (128 ci)
        int j = t & 7, ln = (t >> 3) & 63, Mf = (t >> 9) & 3, rem = t >> 11;
        int tap = rem % 9, c = rem / 9;
        int o = Mf * 16 + (ln & 15);
        int ci = c * 32 + ((ln >> 4) & 3) * 8 + j;
        wA1[t] = f2bf(fw[(o * 128 + ci) * 9 + tap]);
    } else if (t < 73728 + 36864) {                    // conv2: 2 chunks (64 ci)
        int i = t - 73728;
        int j = i & 7, ln = (i >> 3) & 63, Mf = (i >> 9) & 3, rem = i >> 11;
        int tap = rem % 9, c = rem / 9;
        int o = Mf * 16 + (ln & 15);
        int ci = c * 32 + ((ln >> 4) & 3) * 8 + j;
        wA2[i] = f2bf(aw[(o * 64 + ci) * 9 + tap]);
    }
}

// ---------------------------------------------------------------------------
// Transpose f32 [64][npix] -> bf16 channel-last [npix][rowShorts] (cols 0..63)
// ---------------------------------------------------------------------------
__global__ __launch_bounds__(256) void k_tr(const float* __restrict__ src,
                                            ushort* __restrict__ dst,
                                            int npix, int rowShorts) {
    __shared__ float lds[64][65];
    int t = threadIdx.x;
    int pix0 = blockIdx.x * 64;
    int lx = t & 63, ty = t >> 6;
    #pragma unroll
    for (int cc = 0; cc < 64; cc += 4) {
        int c = cc + ty;
        lds[c][lx] = src[(size_t)c * npix + pix0 + lx];
    }
    __syncthreads();
    int cp = t & 31, po = t >> 5;        // cp = channel pair, po = pixel offset
    #pragma unroll
    for (int pl = po; pl < 64; pl += 8) {
        uint u = (uint)f2bf(lds[2 * cp][pl]) | ((uint)f2bf(lds[2 * cp + 1][pl]) << 16);
        *(uint*)(dst + (size_t)(pix0 + pl) * rowShorts + cp * 2) = u;
    }
}

// zero line at ZOFF, -3.4e38 (bf16 pair pattern) line at NEGOFF
__global__ void k_zero(uint* __restrict__ rft32) {
    int t = threadIdx.x;
    if (t < 32)       rft32[(ZOFF >> 2) + t] = 0;
    else if (t < 64)  rft32[(NEGOFF >> 2) + (t - 32)] = 0xFF7FFF7Fu;
}

// ---------------------------------------------------------------------------
// Flow sampling v9 (round-12 proven: 112.5us/dispatch, FETCH 0.39GB): two
// sequential dispatches (sel=0: table rows [0,32); sel=1: [32,64)) -- launch
// boundary = free global phase barrier halving the live footprint to 8.4MB.
// Max merged through xin bf16. 2-ballot partition; trip = max(cntA,cntB);
// surplus iters read NEGOFF sentinel (w00=1, -3.4e38, neutral, L1-resident).
// ---------------------------------------------------------------------------
__global__ __launch_bounds__(256) void k_sample(const float* __restrict__ flow,
                                                const char* __restrict__ rftb,
                                                ushort* __restrict__ xin,
                                                int sel, int mergePrev) {
    __shared__ __align__(16) uint pbuf[4][2][33][8];   // [wave][half][entry][(off,w)x4]
    int tid = threadIdx.x;
    int ln = tid & 63;
    int wid = tid >> 6;
    int half = ln >> 5;
    int gwave = blockIdx.x * 4 + wid;

    // ---- prep (per-lane: one (pixel,k)) ----
    int k = ln & 31;
    int pix = gwave * 2 + half;
    const float* fp = flow + (size_t)pix * 64 + 2 * k;
    float gy = __builtin_nontemporal_load(fp);
    float gx = __builtin_nontemporal_load(fp + 1);
    float ix = fmaf(gx, 1024.f, 1023.5f);
    float iy = fmaf(gy, 32.f, 31.5f);
    float xf = floorf(ix), yf = floorf(iy);
    float wx = ix - xf, wy = iy - yf;
    int x0 = (int)xf, y0 = (int)yf;
    bool xv0 = (unsigned)x0 < (unsigned)WR;
    bool xv1 = (unsigned)(x0 + 1) < (unsigned)WR;
    bool yv0 = (unsigned)y0 < (unsigned)HR;
    bool yv1 = (unsigned)(y0 + 1) < (unsigned)HR;
    int xc0 = x0 < 0 ? 0 : x0;
    int xc1 = x0 + 1 > WR - 1 ? WR - 1 : x0 + 1;
    int yc0 = y0 < 0 ? 0 : y0;
    int yc1 = y0 + 1 > HR - 1 ? HR - 1 : y0 + 1;
    uint o00 = (xv0 && yv0) ? (uint)(((yc0 << 11) + xc0) << 7) : ZOFF;
    uint o01 = (xv1 && yv0) ? (uint)(((yc0 << 11) + xc1) << 7) : ZOFF;
    uint o10 = (xv0 && yv1) ? (uint)(((yc1 << 11) + xc0) << 7) : ZOFF;
    uint o11 = (xv1 && yv1) ? (uint)(((yc1 << 11) + xc1) << 7) : ZOFF;
    float w00 = (1.f - wy) * (1.f - wx);
    float w01 = (1.f - wy) * wx;
    float w10 = wy * (1.f - wx);
    float w11 = wy * wx;

    // ---- 2-way partition by slice (in-range compacted to front) ----
    bool isIn = ((yc0 >> 5) == sel);
    unsigned long long hm = half ? 0xFFFFFFFF00000000ull : 0x00000000FFFFFFFFull;
    unsigned long long lower = (1ull << ln) - 1ull;
    unsigned long long balIn = __ballot(isIn);
    int cntIn = __popcll(balIn & hm);
    int rankIn = __popcll(balIn & hm & lower);
    int rankOut = __popcll(~balIn & hm & lower);
    int pos = isIn ? rankIn : (cntIn + rankOut);
    *(int4_*)&pbuf[wid][half][pos][0] =
        (int4_){(int)o00, __float_as_int(w00), (int)o01, __float_as_int(w01)};
    *(int4_*)&pbuf[wid][half][pos][4] =
        (int4_){(int)o10, __float_as_int(w10), (int)o11, __float_as_int(w11)};
    if ((ln & 31) == 0) {                                // dummy entry at pos 32
        *(int4_*)&pbuf[wid][half][32][0] =
            (int4_){(int)NEGOFF, __float_as_int(1.0f), (int)ZOFF, 0};
        *(int4_*)&pbuf[wid][half][32][4] = (int4_){(int)ZOFF, 0, (int)ZOFF, 0};
    }
    __syncthreads();

    uint laneByte = (uint)((ln & 31) * 4);
    const uint* pb = &pbuf[wid][half][0][0];
    float mLo = -3.0e38f, mHi = -3.0e38f;
    int cA = __builtin_amdgcn_readlane(cntIn, 0);
    int cB = __builtin_amdgcn_readlane(cntIn, 32);
    int trip = cA > cB ? cA : cB;

    for (int i = 0; i < trip; i++) {
        int idx = (i < cntIn) ? i : 32;
        const uint* e = pb + idx * 8;
        uint2 e0 = *(const uint2*)(e + 0);               // ds_read_b64, bcast/half
        uint2 e1 = *(const uint2*)(e + 2);
        uint2 e2 = *(const uint2*)(e + 4);
        uint2 e3 = *(const uint2*)(e + 6);
        uint d0 = *(const uint*)(rftb + (e0.x + laneByte));
        uint d1 = *(const uint*)(rftb + (e1.x + laneByte));
        uint d2 = *(const uint*)(rftb + (e2.x + laneByte));
        uint d3 = *(const uint*)(rftb + (e3.x + laneByte));
        float W0 = __uint_as_float(e0.y);
        float W1 = __uint_as_float(e1.y);
        float W2 = __uint_as_float(e2.y);
        float W3 = __uint_as_float(e3.y);

        float vlo = W0 * __uint_as_float(d0 << 16);
        vlo = fmaf(W1, __uint_as_float(d1 << 16), vlo);
        vlo = fmaf(W2, __uint_as_float(d2 << 16), vlo);
        vlo = fmaf(W3, __uint_as_float(d3 << 16), vlo);
        float vhi = W0 * __uint_as_float(d0 & 0xffff0000u);
        vhi = fmaf(W1, __uint_as_float(d1 & 0xffff0000u), vhi);
        vhi = fmaf(W2, __uint_as_float(d2 & 0xffff0000u), vhi);
        vhi = fmaf(W3, __uint_as_float(d3 & 0xffff0000u), vhi);
        mLo = fmaxf(mLo, vlo);
        mHi = fmaxf(mHi, vhi);
    }

    uint* xp = (uint*)((char*)xin + (size_t)pix * 256 + 128 + (ln & 31) * 4);
    if (mergePrev) {                                     // merge dispatch A's max
        uint cur = __builtin_nontemporal_load(xp);
        mLo = fmaxf(mLo, __uint_as_float(cur << 16));
        mHi = fmaxf(mHi, __uint_as_float(cur & 0xffff0000u));
    }
    uint outw;
    asm("v_cvt_pk_bf16_f32 %0, %1, %2" : "=v"(outw) : "v"(mLo), "v"(mHi));
    __builtin_nontemporal_store(outw, xp);
}

// ---------------------------------------------------------------------------
// conv1: implicit-GEMM MFMA, M=64(o), N=192 (180-px half-row + pad), K=1152.
// Input xin bf16 [p][128]. Output res_bf BF16 [p][64] (BN+ReLU applied).
// (round-12 form -- the reg-staged loop beat gl_lds, batched-staging and
// LDS-free direct-global variants in rounds 13/14/17.)
// ---------------------------------------------------------------------------
__global__ __launch_bounds__(256) void k_mconv1(const ushort* __restrict__ xin,
                                                const ushort* __restrict__ wA,
                                                const float* __restrict__ g,
                                                const float* __restrict__ b,
                                                const float* __restrict__ mn,
                                                const float* __restrict__ vr,
                                                ushort* __restrict__ res_bf) {
    __shared__ __align__(16) ushort xt[3][194][32];
    int tid = threadIdx.x;
    int h = blockIdx.x >> 1, w0 = (blockIdx.x & 1) * 180;
    int wid = tid >> 6, ln = tid & 63;
    f32x4 acc[4][3];
    #pragma unroll
    for (int m = 0; m < 4; m++)
        #pragma unroll
        for (int nf = 0; nf < 3; nf++) acc[m][nf] = (f32x4){0.f, 0.f, 0.f, 0.f};

    for (int c = 0; c < 4; c++) {
        __syncthreads();
        for (int i = tid; i < 2184; i += 256) {          // 546 slots x 4 quads
            int q = i & 3, s = i >> 2;
            int r = s / 182, pw = s - r * 182;
            int gh = h + r - 1;
            int gw = w0 + pw - 1;
            if (gw < 0) gw += WW;
            if (gw >= WW) gw -= WW;
            int4_ val = {0, 0, 0, 0};
            if ((unsigned)gh < (unsigned)HH)
                val = *(const int4_*)(xin + ((size_t)(gh * WW + gw) * 128 + c * 32 + q * 8));
            *(int4_*)&xt[r][pw][(q ^ (pw & 3)) * 8] = val;
        }
        __syncthreads();
        #pragma unroll
        for (int tap = 0; tap < 9; tap++) {
            int dh = tap / 3, dw = tap % 3;
            short8 aF[4];
            #pragma unroll
            for (int m = 0; m < 4; m++)
                aF[m] = *(const short8*)(wA + (size_t)(((c * 9 + tap) * 4 + m) * 64 + ln) * 8);
            short8 bF[3];
            #pragma unroll
            for (int nf = 0; nf < 3; nf++) {
                int pw = wid * 48 + nf * 16 + (ln & 15) + dw;
                bF[nf] = *(const short8*)&xt[dh][pw][((((ln >> 4) & 3)) ^ (pw & 3)) * 8];
            }
            #pragma unroll
            for (int m = 0; m < 4; m++)
                #pragma unroll
                for (int nf = 0; nf < 3; nf++)
                    acc[m][nf] = __builtin_amdgcn_mfma_f32_16x16x32_bf16(aF[m], bF[nf], acc[m][nf], 0, 0, 0);
        }
    }
    // epilogue: BN + ReLU -> res_bf[p][o] (bf16, paired stores)
    #pragma unroll
    for (int m = 0; m < 4; m++) {
        int ob = m * 16 + ((ln >> 4) & 3) * 4;
        float sc0 = g[ob]     * rsqrtf(vr[ob]     + 1e-5f);
        float sc1 = g[ob + 1] * rsqrtf(vr[ob + 1] + 1e-5f);
        float sc2 = g[ob + 2] * rsqrtf(vr[ob + 2] + 1e-5f);
        float sc3 = g[ob + 3] * rsqrtf(vr[ob + 3] + 1e-5f);
        float bi0 = b[ob]     - mn[ob]     * sc0;
        float bi1 = b[ob + 1] - mn[ob + 1] * sc1;
        float bi2 = b[ob + 2] - mn[ob + 2] * sc2;
        float bi3 = b[ob + 3] - mn[ob + 3] * sc3;
        #pragma unroll
        for (int nf = 0; nf < 3; nf++) {
            int n = wid * 48 + nf * 16 + (ln & 15);
            if (n < 180) {
                int P = h * WW + w0 + n;
                float v0 = fmaxf(fmaf(acc[m][nf][0], sc0, bi0), 0.f);
                float v1 = fmaxf(fmaf(acc[m][nf][1], sc1, bi1), 0.f);
                float v2 = fmaxf(fmaf(acc[m][nf][2], sc2, bi2), 0.f);
                float v3 = fmaxf(fmaf(acc[m][nf][3], sc3, bi3), 0.f);
                uint lo, hi;
                asm("v_cvt_pk_bf16_f32 %0, %1, %2" : "=v"(lo) : "v"(v0), "v"(v1));
                asm("v_cvt_pk_bf16_f32 %0, %1, %2" : "=v"(hi) : "v"(v2), "v"(v3));
                uint2 pk; pk.x = lo; pk.y = hi;
                *(uint2*)(res_bf + (size_t)P * 64 + ob) = pk;
            }
        }
    }
}

// ---------------------------------------------------------------------------
// conv2: same GEMM (K=576) on res_bf (bf16, staged raw), BN + channel
// softmax + final out = polar + res*att.  (round-12 form)
// ---------------------------------------------------------------------------
__global__ __launch_bounds__(256) void k_mconv2(const ushort* __restrict__ res_bf,
                                                const float* __restrict__ polar,
                                                const ushort* __restrict__ wA,
                                                const float* __restrict__ g,
                                                const float* __restrict__ b,
                                                const float* __restrict__ mn,
                                                const float* __restrict__ vr,
                                                float* __restrict__ out) {
    __shared__ __align__(16) ushort xt[3][194][32];
    int tid = threadIdx.x;
    int h = blockIdx.x >> 1, w0 = (blockIdx.x & 1) * 180;
    int wid = tid >> 6, ln = tid & 63;
    f32x4 acc[4][3];
    #pragma unroll
    for (int m = 0; m < 4; m++)
        #pragma unroll
        for (int nf = 0; nf < 3; nf++) acc[m][nf] = (f32x4){0.f, 0.f, 0.f, 0.f};

    for (int c = 0; c < 2; c++) {
        __syncthreads();
        for (int i = tid; i < 2184; i += 256) {
            int q = i & 3, s = i >> 2;
            int r = s / 182, pw = s - r * 182;
            int gh = h + r - 1;
            int gw = w0 + pw - 1;
            if (gw < 0) gw += WW;
            if (gw >= WW) gw -= WW;
            int4_ val = {0, 0, 0, 0};
            if ((unsigned)gh < (unsigned)HH)
                val = *(const int4_*)(res_bf + ((size_t)(gh * WW + gw) * 64 + c * 32 + q * 8));
            *(int4_*)&xt[r][pw][(q ^ (pw & 3)) * 8] = val;
        }
        __syncthreads();
        #pragma unroll
        for (int tap = 0; tap < 9; tap++) {
            int dh = tap / 3, dw = tap % 3;
            short8 aF[4];
            #pragma unroll
            for (int m = 0; m < 4; m++)
                aF[m] = *(const short8*)(wA + (size_t)(((c * 9 + tap) * 4 + m) * 64 + ln) * 8);
            short8 bF[3];
            #pragma unroll
            for (int nf = 0; nf < 3; nf++) {
                int pw = wid * 48 + nf * 16 + (ln & 15) + dw;
                bF[nf] = *(const short8*)&xt[dh][pw][((((ln >> 4) & 3)) ^ (pw & 3)) * 8];
            }
            #pragma unroll
            for (int m = 0; m < 4; m++)
                #pragma unroll
                for (int nf = 0; nf < 3; nf++)
                    acc[m][nf] = __builtin_amdgcn_mfma_f32_16x16x32_bf16(aF[m], bF[nf], acc[m][nf], 0, 0, 0);
        }
    }
    // epilogue: BN -> softmax over 64 channels -> out = polar + res*att
    #pragma unroll
    for (int m = 0; m < 4; m++) {
        #pragma unroll
        for (int reg = 0; reg < 4; reg++) {
            int o = m * 16 + ((ln >> 4) & 3) * 4 + reg;
            float sc = g[o] * rsqrtf(vr[o] + 1e-5f);
            float bi = b[o] - mn[o] * sc;
            #pragma unroll
            for (int nf = 0; nf < 3; nf++)
                acc[m][nf][reg] = fmaf(acc[m][nf][reg], sc, bi);
        }
    }
    #pragma unroll
    for (int nf = 0; nf < 3; nf++) {
        float mx = -3.0e38f;
        #pragma unroll
        for (int m = 0; m < 4; m++)
            #pragma unroll
            for (int reg = 0; reg < 4; reg++) mx = fmaxf(mx, acc[m][nf][reg]);
        mx = fmaxf(mx, __shfl_xor(mx, 16));
        mx = fmaxf(mx, __shfl_xor(mx, 32));
        float s = 0.f;
        #pragma unroll
        for (int m = 0; m < 4; m++)
            #pragma unroll
            for (int reg = 0; reg < 4; reg++) {
                float e = __expf(acc[m][nf][reg] - mx);
                acc[m][nf][reg] = e;
                s += e;
            }
        s += __shfl_xor(s, 16);
        s += __shfl_xor(s, 32);
        float rinv = 1.f / s;
        int n = wid * 48 + nf * 16 + (ln & 15);
        if (n < 180) {
            int P = h * WW + w0 + n;
            #pragma unroll
            for (int m = 0; m < 4; m++)
                #pragma unroll
                for (int reg = 0; reg < 4; reg++) {
                    int o = m * 16 + ((ln >> 4) & 3) * 4 + reg;
                    float att = acc[m][nf][reg] * rinv;
                    float rv = __uint_as_float((uint)res_bf[(size_t)P * 64 + o] << 16);
                    out[(size_t)o * NPIX + P] =
                        fmaf(rv, att, polar[(size_t)o * NPIX + P]);
                }
        }
    }
}

// ---------------------------------------------------------------------------
extern "C" void kernel_launch(void* const* d_in, const int* in_sizes, int n_in,
                              void* d_out, int out_size, void* d_ws, size_t ws_size,
                              hipStream_t stream) {
    const float* flow  = (const float*)d_in[0];
    const float* polar = (const float*)d_in[1];
    const float* rf    = (const float*)d_in[2];
    const float* fw    = (const float*)d_in[3];
    const float* fg    = (const float*)d_in[4];
    const float* fb    = (const float*)d_in[5];
    const float* fm    = (const float*)d_in[6];
    const float* fv    = (const float*)d_in[7];
    const float* aw    = (const float*)d_in[8];
    const float* ag    = (const float*)d_in[9];
    const float* ab    = (const float*)d_in[10];
    const float* am    = (const float*)d_in[11];
    const float* av    = (const float*)d_in[12];
    float* out = (float*)d_out;

    char* wsb = (char*)d_ws;
    ushort* xin    = (ushort*)wsb;                        // [NPIX][128] bf16 = 44,236,800 B
    ushort* rft    = (ushort*)(wsb + 44236800);           // [RFNPIX][64] bf16 + sentinel lines
    ushort* res_bf = (ushort*)(wsb + 61014272);           // [NPIX][64] bf16 = 22,118,400 B
    ushort* wA1    = (ushort*)(wsb + 83132672);           // 147,456 B
    ushort* wA2    = wA1 + 73728;                         // 73,728 B

    k_wprep<<<432, 256, 0, stream>>>(fw, aw, wA1, wA2);
    k_tr<<<NPIX / 64, 256, 0, stream>>>(polar, xin, NPIX, 128);
    k_tr<<<RFNPIX / 64, 256, 0, stream>>>(rf, rft, RFNPIX, 64);
    k_zero<<<1, 64, 0, stream>>>((uint*)rft);
    k_sample<<<NPIX / 8, 256, 0, stream>>>(flow, (const char*)rft, xin, 0, 0);
    k_sample<<<NPIX / 8, 256, 0, stream>>>(flow, (const char*)rft, xin, 1, 1);
    k_mconv1<<<960, 256, 0, stream>>>(xin, wA1, fg, fb, fm, fv, res_bf);
    k_mconv2<<<960, 256, 0, stream>>>(res_bf, polar, wA2, ag, ab, am, av, out);
}